// Round 2
// baseline (427.654 us; speedup 1.0000x reference)
//
#include <hip/hip_runtime.h>
#include <hip/hip_bf16.h>

typedef __attribute__((ext_vector_type(8))) short short8;
typedef __attribute__((ext_vector_type(4))) float floatx4;

#define MFMA16(a, b, c) __builtin_amdgcn_mfma_f32_16x16x32_bf16((a), (b), (c), 0, 0, 0)

// Problem dims (fixed by setup_inputs)
static constexpr int Bb = 32, Nn = 864, Cc = 768, Hh = 12, Dd = 64;
static constexpr int Mm = Bb * Nn;      // 27648
static constexpr int NQKV = 3 * Cc;     // 2304

__device__ __forceinline__ void gload_lds16(const __hip_bfloat16* g, __hip_bfloat16* l) {
    __builtin_amdgcn_global_load_lds((const __attribute__((address_space(1))) void*)g,
                                     (__attribute__((address_space(3))) void*)l, 16, 0, 0);
}

// ---------------- f32 -> bf16 elementwise convert ----------------
__global__ __launch_bounds__(256) void cvt_f32_bf16(const float* __restrict__ in,
                                                    __hip_bfloat16* __restrict__ out, int n4) {
    const int i = blockIdx.x * 256 + threadIdx.x;
    if (i >= n4) return;
    const float4 v = ((const float4*)in)[i];
    __hip_bfloat16 o[4] = {__float2bfloat16(v.x), __float2bfloat16(v.y),
                           __float2bfloat16(v.z), __float2bfloat16(v.w)};
    ((uint2*)out)[i] = *(const uint2*)o;
}

// ---------------- transpose + convert (f32 in, bf16 out), R x C -> C x R --------
__global__ __launch_bounds__(256) void transpose_cvt(const float* __restrict__ in,
                                                     __hip_bfloat16* __restrict__ out,
                                                     int R, int C) {
    __shared__ float tile[32][33];
    const int c0 = blockIdx.x * 32;
    const int r0 = blockIdx.y * 32;
    const int tx = threadIdx.x & 31, ty = threadIdx.x >> 5;  // ty 0..7
#pragma unroll
    for (int i = 0; i < 32; i += 8)
        tile[ty + i][tx] = in[(size_t)(r0 + ty + i) * C + c0 + tx];
    __syncthreads();
#pragma unroll
    for (int i = 0; i < 32; i += 8)
        out[(size_t)(c0 + ty + i) * R + r0 + tx] = __float2bfloat16(tile[tx][ty + i]);
}

// ---------------- GEMM: C[M x Nout] = A[M x K] * BT[Nout x K]^T ----------------
// m97 structure: 128x128 block tile, 4 waves each 64x64 (4x4 of 16x16x32 MFMA),
// BK=32, global_load_lds width-16 staging, single LDS buffer.
template <typename OutT>
__global__ __launch_bounds__(256) void gemm_bt(const __hip_bfloat16* __restrict__ A,
                                               const __hip_bfloat16* __restrict__ BT,
                                               OutT* __restrict__ Cout,
                                               const float* __restrict__ bias,
                                               int K, int Nout) {
    __shared__ __align__(16) __hip_bfloat16 As[128 * 32];
    __shared__ __align__(16) __hip_bfloat16 Bs[128 * 32];
    const int m0 = blockIdx.x * 128, n0 = blockIdx.y * 128;
    const int t = threadIdx.x;
    const int lane = t & 63, wave = t >> 6;
    const int wm = (wave >> 1) * 64, wn = (wave & 1) * 64;
    const int ln = lane & 15, quad = lane >> 4;

    floatx4 acc[4][4] = {};

    const int r0 = t >> 2;          // 0..63
    const int cst = (t & 3) * 8;    // 0,8,16,24
    const __hip_bfloat16* Ag = A + (size_t)(m0 + r0) * K + cst;
    const __hip_bfloat16* Bg = BT + (size_t)(n0 + r0) * K + cst;
    const size_t rowskip = (size_t)64 * K;

    for (int k0 = 0; k0 < K; k0 += 32) {
        gload_lds16(Ag + k0,           &As[t * 8]);
        gload_lds16(Ag + k0 + rowskip, &As[2048 + t * 8]);
        gload_lds16(Bg + k0,           &Bs[t * 8]);
        gload_lds16(Bg + k0 + rowskip, &Bs[2048 + t * 8]);
        __syncthreads();

        short8 af[4], bfr[4];
#pragma unroll
        for (int i = 0; i < 4; i++)
            af[i] = *(const short8*)&As[(wm + i * 16 + ln) * 32 + quad * 8];
#pragma unroll
        for (int j = 0; j < 4; j++)
            bfr[j] = *(const short8*)&Bs[(wn + j * 16 + ln) * 32 + quad * 8];
#pragma unroll
        for (int i = 0; i < 4; i++)
#pragma unroll
            for (int j = 0; j < 4; j++)
                acc[i][j] = MFMA16(af[i], bfr[j], acc[i][j]);
        __syncthreads();
    }

    // Epilogue. C/D layout: row = quad*4 + r, col = ln (verified m89/m91)
#pragma unroll
    for (int j = 0; j < 4; j++) {
        const int n = n0 + wn + j * 16 + ln;
        const float bv = bias ? bias[n] : 0.0f;
#pragma unroll
        for (int i = 0; i < 4; i++) {
            const int mrow = m0 + wm + i * 16 + quad * 4;
#pragma unroll
            for (int r = 0; r < 4; r++) {
                const float val = acc[i][j][r] + bv;
                if constexpr (__is_same(OutT, float))
                    Cout[(size_t)(mrow + r) * Nout + n] = val;
                else
                    Cout[(size_t)(mrow + r) * Nout + n] = __float2bfloat16(val);
            }
        }
    }
}

// ---------------- fused cross attention ----------------
// qkv layout: [b*864 + n][2304] with cols: q = h*64+d, k = 768+h*64+d, v = 1536+h*64+d
// part t: queries [0,288), keys/values rows [72,216) (L=144)
// part s: queries [288,864), keys/values rows [0,72)  (L=72)
static constexpr int STR = 168;  // padded LDS stride for VT and P (max Lpad 160 + 8)

template <int L, int QOFF, int KVOFF, int NQT, int STILES, int NPV>
__device__ __forceinline__ void attn_part(const __hip_bfloat16* __restrict__ qkv,
                                          __hip_bfloat16* __restrict__ attn,
                                          int b, int h,
                                          __hip_bfloat16* Ks, __hip_bfloat16* VTs,
                                          __hip_bfloat16* Ps) {
    const int t = threadIdx.x, lane = t & 63, wave = t >> 6;
    const int ln = lane & 15, quad = lane >> 4;
    const __hip_bfloat16 z16 = __float2bfloat16(0.0f);

    const __hip_bfloat16* kbase = qkv + ((size_t)(b * 864 + KVOFF)) * 2304 + 768 + h * 64;
    const __hip_bfloat16* vbase = kbase + 768;

    // stage K rows [0, STILES*16), zero-pad rows >= L. row stride 72 (=64+8 pad)
    for (int c = t; c < STILES * 16 * 8; c += 256) {
        const int key = c >> 3, d0 = (c & 7) * 8;
        uint4 val = make_uint4(0u, 0u, 0u, 0u);
        if (key < L) val = *(const uint4*)(kbase + (size_t)key * 2304 + d0);
        *(uint4*)&Ks[key * 72 + d0] = val;
    }
    // stage V transposed: VT[dd][key], keys zero-padded to NPV*32
    for (int c = t; c < NPV * 32 * 8; c += 256) {
        const int key = c >> 3, d0 = (c & 7) * 8;
        if (key < L) {
            uint4 raw = *(const uint4*)(vbase + (size_t)key * 2304 + d0);
            const __hip_bfloat16* pv = (const __hip_bfloat16*)&raw;
#pragma unroll
            for (int jj = 0; jj < 8; jj++) VTs[(d0 + jj) * STR + key] = pv[jj];
        } else {
#pragma unroll
            for (int jj = 0; jj < 8; jj++) VTs[(d0 + jj) * STR + key] = z16;
        }
    }
    // zero P scratch (pad columns must be 0 for the PV MFMAs)
    for (int c = t; c < 4 * 16 * STR; c += 256) Ps[c] = z16;
    __syncthreads();

    __hip_bfloat16* Pw = &Ps[wave * 16 * STR];
    const float scale = 0.125f;  // d^-0.5, d=64

    for (int qt = wave; qt < NQT; qt += 4) {
        const __hip_bfloat16* qrow =
            qkv + (size_t)(b * 864 + QOFF + qt * 16 + ln) * 2304 + h * 64;
        const short8 aq0 = *(const short8*)(qrow + quad * 8);
        const short8 aq1 = *(const short8*)(qrow + 32 + quad * 8);

        float sv[STILES][4];
        float pm[4] = {-3e30f, -3e30f, -3e30f, -3e30f};
#pragma unroll
        for (int kt = 0; kt < STILES; kt++) {
            floatx4 acc = {0.f, 0.f, 0.f, 0.f};
            const __hip_bfloat16* krow = &Ks[(kt * 16 + ln) * 72];
            const short8 b0 = *(const short8*)(krow + quad * 8);
            const short8 b1 = *(const short8*)(krow + 32 + quad * 8);
            acc = MFMA16(aq0, b0, acc);
            acc = MFMA16(aq1, b1, acc);
            const bool valid = (kt * 16 + ln) < L;
#pragma unroll
            for (int r = 0; r < 4; r++) {
                const float s = valid ? acc[r] * scale : -3e30f;
                sv[kt][r] = s;
                pm[r] = fmaxf(pm[r], s);
            }
        }
        // row stats live on the 16 lanes sharing `quad` (row = quad*4+r)
#pragma unroll
        for (int off = 1; off < 16; off <<= 1)
#pragma unroll
            for (int r = 0; r < 4; r++) pm[r] = fmaxf(pm[r], __shfl_xor(pm[r], off));
        float psum[4] = {0.f, 0.f, 0.f, 0.f};
#pragma unroll
        for (int kt = 0; kt < STILES; kt++)
#pragma unroll
            for (int r = 0; r < 4; r++) {
                const float e = __expf(sv[kt][r] - pm[r]);
                sv[kt][r] = e;
                psum[r] += e;
            }
#pragma unroll
        for (int off = 1; off < 16; off <<= 1)
#pragma unroll
            for (int r = 0; r < 4; r++) psum[r] += __shfl_xor(psum[r], off);

        // P (unnormalized) -> LDS in A-operand layout source (row-major [q][key])
#pragma unroll
        for (int kt = 0; kt < STILES; kt++)
#pragma unroll
            for (int r = 0; r < 4; r++)
                Pw[(quad * 4 + r) * STR + kt * 16 + ln] = __float2bfloat16(sv[kt][r]);

        // O = P @ V  (keys zero-padded to NPV*32)
        floatx4 acco[4] = {};
#pragma unroll
        for (int kk = 0; kk < NPV; kk++) {
            const short8 ap = *(const short8*)&Pw[ln * STR + kk * 32 + quad * 8];
#pragma unroll
            for (int j = 0; j < 4; j++) {
                const short8 bv = *(const short8*)&VTs[(j * 16 + ln) * STR + kk * 32 + quad * 8];
                acco[j] = MFMA16(ap, bv, acco[j]);
            }
        }
        float inv[4];
#pragma unroll
        for (int r = 0; r < 4; r++) inv[r] = 1.0f / psum[r];
#pragma unroll
        for (int j = 0; j < 4; j++)
#pragma unroll
            for (int r = 0; r < 4; r++) {
                const int nseq = QOFF + qt * 16 + quad * 4 + r;
                attn[(size_t)(b * 864 + nseq) * 768 + h * 64 + j * 16 + ln] =
                    __float2bfloat16(acco[j][r] * inv[r]);
            }
    }
}

__global__ __launch_bounds__(256) void attn_kernel(const __hip_bfloat16* __restrict__ qkv,
                                                   __hip_bfloat16* __restrict__ attn) {
    __shared__ __align__(16) __hip_bfloat16 Ks[144 * 72];       // 20736 B
    __shared__ __align__(16) __hip_bfloat16 VTs[64 * STR];      // 21504 B
    __shared__ __align__(16) __hip_bfloat16 Ps[4 * 16 * STR];   // 21504 B
    const int part = blockIdx.x & 1;
    const int bh = blockIdx.x >> 1;
    const int b = bh / 12, h = bh % 12;
    if (part == 0)
        attn_part<144, 0, 72, 18, 9, 5>(qkv, attn, b, h, Ks, VTs, Ps);   // t-part
    else
        attn_part<72, 288, 0, 36, 5, 3>(qkv, attn, b, h, Ks, VTs, Ps);   // s-part
}

// ---------------- launch ----------------
extern "C" void kernel_launch(void* const* d_in, const int* in_sizes, int n_in,
                              void* d_out, int out_size, void* d_ws, size_t ws_size,
                              hipStream_t stream) {
    const float* x     = (const float*)d_in[0];
    const float* Wqkv  = (const float*)d_in[1];
    const float* Wproj = (const float*)d_in[2];
    const float* bproj = (const float*)d_in[3];
    float* out = (float*)d_out;

    // workspace layout (bytes):
    //   [0, 42467328)            x_bf16  (27648 x 768)   -- later reused as attn
    //   [42467328, 46006272)     WqkvT   (2304 x 768)
    //   [46006272, 47185920)     WprojT  (768 x 768)
    //   [47185920, 174587904)    qkv     (27648 x 2304)
    char* ws = (char*)d_ws;
    __hip_bfloat16* xb     = (__hip_bfloat16*)ws;
    __hip_bfloat16* WqkvT  = (__hip_bfloat16*)(ws + 42467328);
    __hip_bfloat16* WprojT = (__hip_bfloat16*)(ws + 46006272);
    __hip_bfloat16* qkv    = (__hip_bfloat16*)(ws + 47185920);
    __hip_bfloat16* attn   = (__hip_bfloat16*)ws;  // alias xb: x fully consumed before attention

    const int nx4 = Mm * Cc / 4;  // 5,308,416 float4s
    cvt_f32_bf16<<<(nx4 + 255) / 256, 256, 0, stream>>>(x, xb, nx4);
    transpose_cvt<<<dim3(NQKV / 32, Cc / 32), 256, 0, stream>>>(Wqkv, WqkvT, Cc, NQKV);
    transpose_cvt<<<dim3(Cc / 32, Cc / 32), 256, 0, stream>>>(Wproj, WprojT, Cc, Cc);
    gemm_bt<__hip_bfloat16><<<dim3(Mm / 128, NQKV / 128), 256, 0, stream>>>(xb, WqkvT, qkv, nullptr, Cc, NQKV);
    attn_kernel<<<Bb * Hh * 2, 256, 0, stream>>>(qkv, attn);
    gemm_bt<float><<<dim3(Mm / 128, Cc / 128), 256, 0, stream>>>(attn, WprojT, out, bproj, Cc, Cc);
}